// Round 16
// baseline (4547.516 us; speedup 1.0000x reference)
//
#include <hip/hip_runtime.h>
#include <cstdint>
#include <math.h>

// Problem constants (match reference)
#define N_ATOMS 30000
#define E_EDGES 200000
#define T_TRI   400000
#define D_DIM   128
#define H_HEADS 8
#define F_FEAT  16
#define CLS     6

// bf16 helpers (RNE pack, bit-shift unpack)
static __device__ __forceinline__ unsigned short f2bf(float f) {
    union { float f; unsigned u; } v; v.f = f;
    unsigned r = v.u + 0x7FFFu + ((v.u >> 16) & 1u);
    return (unsigned short)(r >> 16);
}
static __device__ __forceinline__ void bf2x(unsigned u, float& a, float& b) {
    union { unsigned u; float f; } x, y;
    x.u = u << 16; y.u = u & 0xFFFF0000u;
    a = x.f; b = y.f;
}

// ---------------------------------------------------------------------------
// Kernel 1: 6-row angle MLP -> ae_table[6][128]
// ---------------------------------------------------------------------------
__launch_bounds__(256)
__global__ void ang_mlp_kernel(const float* __restrict__ tab,
                               const float* __restrict__ W0, const float* __restrict__ b0,
                               const float* __restrict__ W1, const float* __restrict__ b1,
                               const float* __restrict__ W2, const float* __restrict__ b2,
                               float* __restrict__ out)
{
    __shared__ float bufA[CLS * D_DIM];
    __shared__ float bufB[CLS * D_DIM];
    __shared__ float Wl[D_DIM * D_DIM];
    const int tid = threadIdx.x;
    for (int i = tid; i < CLS * D_DIM; i += 256) bufA[i] = tab[i];
    const float* Ws[3] = {W0, W1, W2};
    const float* bs[3] = {b0, b1, b2};
    float* in  = bufA;
    float* ob  = bufB;
    for (int l = 0; l < 3; ++l) {
        __syncthreads();
        for (int i = tid * 4; i < D_DIM * D_DIM; i += 256 * 4)
            *(float4*)&Wl[i] = *(const float4*)&Ws[l][i];
        __syncthreads();
        for (int o = tid; o < CLS * D_DIM; o += 256) {
            const int r = o >> 7, c = o & 127;
            float acc = bs[l][c];
            #pragma unroll 8
            for (int k = 0; k < D_DIM; ++k) acc += in[r * D_DIM + k] * Wl[k * D_DIM + c];
            ob[o] = fmaxf(acc, 0.f);
        }
        float* t = in; in = ob; ob = t;
    }
    __syncthreads();
    for (int i = tid; i < CLS * D_DIM; i += 256) out[i] = in[i];
}

// ---------------------------------------------------------------------------
// Kernel 2: bins — strict unfused f32 (a,b) in numpy op order, CR f32 atan2
// via f64, f32 divide, trunc, clip.  DEGENERATE-SIGN FIX: for b==0 and
// a == -0.0 (bit 0x80000000; happens for idx_j==idx_i triplets whose k-vector
// has all-negative components: products are all -0, sum keeps -0), IEEE
// atan2(+0,-0)=pi -> bin 5, but the np reference's SVML f32 arctan2 (AVX-512
// dispatch) does not honor the (0,-0) branch cut and returns 0 -> bin 0.
// This is the ONLY triplet class excluded from every prior flip experiment
// (R5/R11/R12 required m in [1,5]; R13 required b>0, r2>0).
// ---------------------------------------------------------------------------
__launch_bounds__(256)
__global__ void tri_bins_kernel(const float* __restrict__ pos,
                                const int* __restrict__ idx_i,
                                const int* __restrict__ idx_j,
                                const int* __restrict__ idx_k,
                                int* __restrict__ bins)
{
    const int t = blockIdx.x * 256 + threadIdx.x;
    if (t >= T_TRI) return;
    const int ii = idx_i[t], jj = idx_j[t], kk = idx_k[t];
    const float pix = pos[3*ii], piy = pos[3*ii+1], piz = pos[3*ii+2];
    const float jx = __fsub_rn(pos[3*jj],   pix);
    const float jy = __fsub_rn(pos[3*jj+1], piy);
    const float jz = __fsub_rn(pos[3*jj+2], piz);
    const float kx = __fsub_rn(pos[3*kk],   pix);
    const float ky = __fsub_rn(pos[3*kk+1], piy);
    const float kz = __fsub_rn(pos[3*kk+2], piz);
    const float a  = __fadd_rn(__fadd_rn(__fmul_rn(jx,kx), __fmul_rn(jy,ky)),
                               __fmul_rn(jz,kz));
    const float cx = __fsub_rn(__fmul_rn(jy,kz), __fmul_rn(jz,ky));
    const float cy = __fsub_rn(__fmul_rn(jz,kx), __fmul_rn(jx,kz));
    const float cz = __fsub_rn(__fmul_rn(jx,ky), __fmul_rn(jy,kx));
    const float ss = __fadd_rn(__fadd_rn(__fmul_rn(cx,cx), __fmul_rn(cy,cy)),
                               __fmul_rn(cz,cz));
    const float b  = __fsqrt_rn(ss);

    int bin;
    if (b == 0.0f && __float_as_uint(a) == 0x80000000u) {
        // atan2(+0, -0): IEEE pi (bin 5) vs reference SVML 0 (bin 0)
        bin = 0;
    } else {
        const float angle = (float)atan2((double)b, (double)a);
        const float c = (float)(3.1415926 / 6.0);
        const float q = __fdiv_rn(angle, c);
        bin = (int)q;
        bin = bin < 0 ? 0 : (bin > CLS - 1 ? CLS - 1 : bin);
    }
    bins[t] = bin;
}

// ---------------------------------------------------------------------------
// Kernel 3: projection GEMM  C_bf16[M,128] = A[M,128] @ W[128,128]
// ---------------------------------------------------------------------------
__launch_bounds__(256)
__global__ void gemm_proj_bf16(const float* __restrict__ A, const float* __restrict__ W,
                               unsigned short* __restrict__ C, int M)
{
    __shared__ float Wl[128 * 128];
    __shared__ float Al[8][128];
    for (int i = threadIdx.x * 4; i < 128 * 128; i += 1024)
        *(float4*)&Wl[i] = *(const float4*)&W[i];
    const int r  = threadIdx.x >> 5;
    const int c4 = (threadIdx.x & 31) * 4;
    const int ntiles = M / 8;
    for (int tile = blockIdx.x; tile < ntiles; tile += gridDim.x) {
        const int row0 = tile * 8;
        __syncthreads();
        for (int i = threadIdx.x; i < 8 * 128; i += 256)
            Al[i >> 7][i & 127] = A[(int64_t)(row0 + (i >> 7)) * 128 + (i & 127)];
        __syncthreads();
        float a0 = 0.f, a1 = 0.f, a2 = 0.f, a3 = 0.f;
        #pragma unroll 8
        for (int k = 0; k < 128; ++k) {
            const float av = Al[r][k];
            const float4 w = *(const float4*)&Wl[k * 128 + c4];
            a0 += av * w.x; a1 += av * w.y; a2 += av * w.z; a3 += av * w.w;
        }
        ushort4 o;
        o.x = f2bf(a0); o.y = f2bf(a1); o.z = f2bf(a2); o.w = f2bf(a3);
        *(ushort4*)&C[(int64_t)(row0 + r) * 128 + c4] = o;
    }
}

// ---------------------------------------------------------------------------
// Kernel 4: FUSED attention + aggregation (softmax division commuted out)
// ---------------------------------------------------------------------------
__launch_bounds__(256)
__global__ void att_agg_kernel(const unsigned short* __restrict__ Kh,
                               const unsigned short* __restrict__ Qh,
                               const unsigned short* __restrict__ Vh,
                               const float* __restrict__ aeT,
                               const int* __restrict__ bins,
                               const int* __restrict__ ikj, const int* __restrict__ iji,
                               const float* __restrict__ battn, const float* __restrict__ disW,
                               float* __restrict__ denom, float* __restrict__ msg)
{
    const int g = blockIdx.x * 256 + threadIdx.x;
    const int t = g >> 3, h = g & 7;
    const int ekj = ikj[t], eji = iji[t];
    const int64_t kb = (int64_t)ekj * D_DIM + h * F_FEAT;
    const int64_t qb = (int64_t)eji * D_DIM + h * F_FEAT;
    const float* ap = aeT + bins[t] * D_DIM + h * F_FEAT;

    const uint4 ka = *(const uint4*)&Kh[kb];
    const uint4 kb2 = *(const uint4*)&Kh[kb + 8];
    const uint4 qa = *(const uint4*)&Qh[qb];
    const uint4 qb2 = *(const uint4*)&Qh[qb + 8];
    const uint4 va = *(const uint4*)&Vh[kb];
    const uint4 vb2 = *(const uint4*)&Vh[kb + 8];
    const float4 e0 = *(const float4*)(ap + 0);
    const float4 e1 = *(const float4*)(ap + 4);
    const float4 e2 = *(const float4*)(ap + 8);
    const float4 e3 = *(const float4*)(ap + 12);

    float kf[16], qf[16], vf[16];
    bf2x(ka.x,  kf[0],  kf[1]);  bf2x(ka.y,  kf[2],  kf[3]);
    bf2x(ka.z,  kf[4],  kf[5]);  bf2x(ka.w,  kf[6],  kf[7]);
    bf2x(kb2.x, kf[8],  kf[9]);  bf2x(kb2.y, kf[10], kf[11]);
    bf2x(kb2.z, kf[12], kf[13]); bf2x(kb2.w, kf[14], kf[15]);
    bf2x(qa.x,  qf[0],  qf[1]);  bf2x(qa.y,  qf[2],  qf[3]);
    bf2x(qa.z,  qf[4],  qf[5]);  bf2x(qa.w,  qf[6],  qf[7]);
    bf2x(qb2.x, qf[8],  qf[9]);  bf2x(qb2.y, qf[10], qf[11]);
    bf2x(qb2.z, qf[12], qf[13]); bf2x(qb2.w, qf[14], qf[15]);
    bf2x(va.x,  vf[0],  vf[1]);  bf2x(va.y,  vf[2],  vf[3]);
    bf2x(va.z,  vf[4],  vf[5]);  bf2x(va.w,  vf[6],  vf[7]);
    bf2x(vb2.x, vf[8],  vf[9]);  bf2x(vb2.y, vf[10], vf[11]);
    bf2x(vb2.z, vf[12], vf[13]); bf2x(vb2.w, vf[14], vf[15]);
    const float aef[16] = {e0.x,e0.y,e0.z,e0.w, e1.x,e1.y,e1.z,e1.w,
                           e2.x,e2.y,e2.z,e2.w, e3.x,e3.y,e3.z,e3.w};

    float dot = 0.f;
    #pragma unroll
    for (int i = 0; i < 16; ++i)
        dot += (kf[i] + aef[i]) * (qf[i] + aef[i]);

    const float ex = expf(dot * 0.25f + battn[ekj] * disW[h]);
    atomicAdd(&denom[(int64_t)eji * H_HEADS + h], ex);
    float* o = msg + (int64_t)eji * D_DIM + h * F_FEAT;
    #pragma unroll
    for (int i = 0; i < 16; ++i)
        atomicAdd(&o[i], ex * (vf[i] + aef[i]));
}

// ---------------------------------------------------------------------------
// Kernel 5: he = msg/denom + bond (in-place in msg), h = LN1(he) -> hout.
// ---------------------------------------------------------------------------
__launch_bounds__(256)
__global__ void he_ln1_kernel(float* __restrict__ msg, const float* __restrict__ denom,
                              const float* __restrict__ bond,
                              const float* __restrict__ g1, const float* __restrict__ b1,
                              float* __restrict__ hout)
{
    const int wave = (blockIdx.x * 256 + threadIdx.x) >> 6;
    const int lane = threadIdx.x & 63;
    if (wave >= E_EDGES) return;
    const int64_t base = (int64_t)wave * D_DIM;
    const float den0 = denom[wave * 8 + (lane >> 4)];
    const float den1 = denom[wave * 8 + (lane >> 4) + 4];
    const float m0 = msg[base + lane], m1 = msg[base + 64 + lane];
    const float x0 = (den0 > 0.f ? m0 / den0 : 0.f) + bond[base + lane];
    const float x1 = (den1 > 0.f ? m1 / den1 : 0.f) + bond[base + 64 + lane];
    msg[base + lane]      = x0;
    msg[base + 64 + lane] = x1;
    float s = x0 + x1;
    #pragma unroll
    for (int o = 32; o > 0; o >>= 1) s += __shfl_xor(s, o);
    const float m = s * (1.f / 128.f);
    const float d0 = x0 - m, d1 = x1 - m;
    float v = d0 * d0 + d1 * d1;
    #pragma unroll
    for (int o = 32; o > 0; o >>= 1) v += __shfl_xor(v, o);
    const float rs = rsqrtf(v * (1.f / 128.f) + 1e-5f);
    hout[base + lane]      = d0 * rs * g1[lane]      + b1[lane];
    hout[base + 64 + lane] = d1 * rs * g1[lane + 64] + b1[lane + 64];
}

// ---------------------------------------------------------------------------
// Kernel 6: fused FFN + residual + LN2, in-place on d_out.
// ---------------------------------------------------------------------------
__launch_bounds__(256)
__global__ void ffn_ln2_kernel(const float* __restrict__ hin,
                               const float* __restrict__ he,
                               const float* __restrict__ W1,
                               const float* __restrict__ W2,
                               const float* __restrict__ g2, const float* __restrict__ b2,
                               float* __restrict__ outp)
{
    __shared__ float hs[16][132];
    __shared__ float W1c[128][64];
    __shared__ float W2c[64][128];
    __shared__ float mid[16][68];
    const int tid = threadIdx.x;
    const int r = tid >> 4;
    const int q = tid & 15;
    const int row = blockIdx.x * 16 + r;

    {
        const int li = tid * 8;
        const int lr = li >> 7, lc = li & 127;
        const float4 v0 = *(const float4*)&hin[(int64_t)(blockIdx.x * 16 + lr) * 128 + lc];
        const float4 v1 = *(const float4*)&hin[(int64_t)(blockIdx.x * 16 + lr) * 128 + lc + 4];
        hs[lr][lc+0] = v0.x; hs[lr][lc+1] = v0.y; hs[lr][lc+2] = v0.z; hs[lr][lc+3] = v0.w;
        hs[lr][lc+4] = v1.x; hs[lr][lc+5] = v1.y; hs[lr][lc+6] = v1.z; hs[lr][lc+7] = v1.w;
    }

    float acc[8] = {0.f,0.f,0.f,0.f,0.f,0.f,0.f,0.f};
    for (int c = 0; c < 4; ++c) {
        __syncthreads();
        for (int i = tid * 4; i < 8192; i += 1024) {
            const int k = i >> 6, m = i & 63;
            *(float4*)&W1c[k][m] = *(const float4*)&W1[k * 256 + c * 64 + m];
        }
        for (int i = tid * 4; i < 8192; i += 1024)
            *(float4*)&W2c[0][i] = *(const float4*)&W2[c * 8192 + i];
        __syncthreads();
        float s0 = 0.f, s1 = 0.f, s2 = 0.f, s3 = 0.f;
        #pragma unroll 8
        for (int k = 0; k < 128; ++k) {
            const float hv = hs[r][k];
            const float4 w = *(const float4*)&W1c[k][q * 4];
            s0 += hv * w.x; s1 += hv * w.y; s2 += hv * w.z; s3 += hv * w.w;
        }
        mid[r][q*4+0] = fmaxf(s0, 0.f);
        mid[r][q*4+1] = fmaxf(s1, 0.f);
        mid[r][q*4+2] = fmaxf(s2, 0.f);
        mid[r][q*4+3] = fmaxf(s3, 0.f);
        __syncthreads();
        #pragma unroll 8
        for (int m = 0; m < 64; ++m) {
            const float mv = mid[r][m];
            const float4 w0 = *(const float4*)&W2c[m][q * 8];
            const float4 w1 = *(const float4*)&W2c[m][q * 8 + 4];
            acc[0] += mv * w0.x; acc[1] += mv * w0.y; acc[2] += mv * w0.z; acc[3] += mv * w0.w;
            acc[4] += mv * w1.x; acc[5] += mv * w1.y; acc[6] += mv * w1.z; acc[7] += mv * w1.w;
        }
    }

    const int64_t ob = (int64_t)row * 128;
    const float4 h0 = *(const float4*)&he[ob + q * 8];
    const float4 h1 = *(const float4*)&he[ob + q * 8 + 4];
    float x0 = acc[0] + h0.x, x1 = acc[1] + h0.y, x2 = acc[2] + h0.z, x3 = acc[3] + h0.w;
    float x4 = acc[4] + h1.x, x5 = acc[5] + h1.y, x6 = acc[6] + h1.z, x7 = acc[7] + h1.w;
    float s = x0 + x1 + x2 + x3 + x4 + x5 + x6 + x7;
    #pragma unroll
    for (int o = 8; o > 0; o >>= 1) s += __shfl_xor(s, o);
    const float mean = s * (1.f / 128.f);
    float v = (x0-mean)*(x0-mean) + (x1-mean)*(x1-mean) + (x2-mean)*(x2-mean) + (x3-mean)*(x3-mean)
            + (x4-mean)*(x4-mean) + (x5-mean)*(x5-mean) + (x6-mean)*(x6-mean) + (x7-mean)*(x7-mean);
    #pragma unroll
    for (int o = 8; o > 0; o >>= 1) v += __shfl_xor(v, o);
    const float rs = rsqrtf(v * (1.f / 128.f) + 1e-5f);
    const int fb = q * 8;
    float4 o0, o1;
    o0.x = (x0-mean)*rs*g2[fb+0] + b2[fb+0];
    o0.y = (x1-mean)*rs*g2[fb+1] + b2[fb+1];
    o0.z = (x2-mean)*rs*g2[fb+2] + b2[fb+2];
    o0.w = (x3-mean)*rs*g2[fb+3] + b2[fb+3];
    o1.x = (x4-mean)*rs*g2[fb+4] + b2[fb+4];
    o1.y = (x5-mean)*rs*g2[fb+5] + b2[fb+5];
    o1.z = (x6-mean)*rs*g2[fb+6] + b2[fb+6];
    o1.w = (x7-mean)*rs*g2[fb+7] + b2[fb+7];
    *(float4*)&outp[ob + q * 8]     = o0;
    *(float4*)&outp[ob + q * 8 + 4] = o1;
}

// ---------------------------------------------------------------------------
extern "C" void kernel_launch(void* const* d_in, const int* in_sizes, int n_in,
                              void* d_out, int out_size, void* d_ws, size_t ws_size,
                              hipStream_t stream)
{
    const float* bond     = (const float*)d_in[0];
    const float* pos      = (const float*)d_in[1];
    const float* battn    = (const float*)d_in[2];
    const float* ang_tab  = (const float*)d_in[3];
    const float* ang_in_W = (const float*)d_in[4];
    const float* ang_in_b = (const float*)d_in[5];
    const float* ang2_W   = (const float*)d_in[6];
    const float* ang2_b   = (const float*)d_in[7];
    const float* ang1_W   = (const float*)d_in[8];
    const float* ang1_b   = (const float*)d_in[9];
    const float* k_W      = (const float*)d_in[10];
    const float* q_W      = (const float*)d_in[11];
    const float* v_W      = (const float*)d_in[12];
    const float* dis_W    = (const float*)d_in[13];
    const float* ffn_W1   = (const float*)d_in[14];
    const float* ffn_W2   = (const float*)d_in[15];
    const float* ln1_g    = (const float*)d_in[16];
    const float* ln1_b    = (const float*)d_in[17];
    const float* ln2_g    = (const float*)d_in[18];
    const float* ln2_b    = (const float*)d_in[19];
    const int*   index_kj = (const int*)d_in[20];
    const int*   index_ji = (const int*)d_in[21];
    const int*   idx_i    = (const int*)d_in[22];
    const int*   idx_j    = (const int*)d_in[23];
    const int*   idx_k    = (const int*)d_in[24];

    float* ws = (float*)d_ws;
    // ws layout (float offsets) — ~161 MB, no overlaps
    float*          denom = ws;                                   // 1,600,000
    int*            bins  = (int*)(ws + 1600000);                 //   400,000
    float*          aeT   = ws + 2000000;                         //       768
    float*          msg   = ws + 2002048;                         // 25,600,000
    unsigned short* Vh    = (unsigned short*)(ws + 27602048);     // 25,600,000 bf16

    // d_out doubles as K/Q bf16 storage, then h, then final out
    unsigned short* Kh = (unsigned short*)d_out;
    unsigned short* Qh = Kh + 25600000;
    float*          hb = (float*)d_out;
    float*          out = (float*)d_out;

    hipMemsetAsync(denom, 0, (size_t)E_EDGES * H_HEADS * sizeof(float), stream);
    hipMemsetAsync(msg,   0, (size_t)E_EDGES * D_DIM * sizeof(float), stream);

    ang_mlp_kernel<<<1, 256, 0, stream>>>(ang_tab, ang_in_W, ang_in_b,
                                          ang2_W, ang2_b, ang1_W, ang1_b, aeT);
    tri_bins_kernel<<<(T_TRI + 255) / 256, 256, 0, stream>>>(pos, idx_i, idx_j, idx_k, bins);

    gemm_proj_bf16<<<512, 256, 0, stream>>>(bond, k_W, Kh, E_EDGES);
    gemm_proj_bf16<<<512, 256, 0, stream>>>(bond, q_W, Qh, E_EDGES);
    gemm_proj_bf16<<<512, 256, 0, stream>>>(bond, v_W, Vh, E_EDGES);

    att_agg_kernel<<<(T_TRI * H_HEADS) / 256, 256, 0, stream>>>(
        Kh, Qh, Vh, aeT, bins, index_kj, index_ji, battn, dis_W, denom, msg);

    he_ln1_kernel<<<E_EDGES / 4, 256, 0, stream>>>(msg, denom, bond, ln1_g, ln1_b, hb);

    ffn_ln2_kernel<<<E_EDGES / 16, 256, 0, stream>>>(hb, msg, ffn_W1, ffn_W2,
                                                     ln2_g, ln2_b, out);
}

// Round 17
// 1626.336 us; speedup vs baseline: 2.7962x; 2.7962x over previous
//
#include <hip/hip_runtime.h>
#include <cstdint>
#include <math.h>

// Problem constants (match reference)
#define N_ATOMS 30000
#define E_EDGES 200000
#define T_TRI   400000
#define D_DIM   128
#define H_HEADS 8
#define F_FEAT  16
#define CLS     6

// bf16 helpers (RNE pack, bit-shift unpack)
static __device__ __forceinline__ unsigned short f2bf(float f) {
    union { float f; unsigned u; } v; v.f = f;
    unsigned r = v.u + 0x7FFFu + ((v.u >> 16) & 1u);
    return (unsigned short)(r >> 16);
}
static __device__ __forceinline__ void bf2x(unsigned u, float& a, float& b) {
    union { unsigned u; float f; } x, y;
    x.u = u << 16; y.u = u & 0xFFFF0000u;
    a = x.f; b = y.f;
}

// ---------------------------------------------------------------------------
// Kernel 1: 6-row angle MLP -> ae_table[6][128]
// ---------------------------------------------------------------------------
__launch_bounds__(256)
__global__ void ang_mlp_kernel(const float* __restrict__ tab,
                               const float* __restrict__ W0, const float* __restrict__ b0,
                               const float* __restrict__ W1, const float* __restrict__ b1,
                               const float* __restrict__ W2, const float* __restrict__ b2,
                               float* __restrict__ out)
{
    __shared__ float bufA[CLS * D_DIM];
    __shared__ float bufB[CLS * D_DIM];
    __shared__ float Wl[D_DIM * D_DIM];
    const int tid = threadIdx.x;
    for (int i = tid; i < CLS * D_DIM; i += 256) bufA[i] = tab[i];
    const float* Ws[3] = {W0, W1, W2};
    const float* bs[3] = {b0, b1, b2};
    float* in  = bufA;
    float* ob  = bufB;
    for (int l = 0; l < 3; ++l) {
        __syncthreads();
        for (int i = tid * 4; i < D_DIM * D_DIM; i += 256 * 4)
            *(float4*)&Wl[i] = *(const float4*)&Ws[l][i];
        __syncthreads();
        for (int o = tid; o < CLS * D_DIM; o += 256) {
            const int r = o >> 7, c = o & 127;
            float acc = bs[l][c];
            #pragma unroll 8
            for (int k = 0; k < D_DIM; ++k) acc += in[r * D_DIM + k] * Wl[k * D_DIM + c];
            ob[o] = fmaxf(acc, 0.f);
        }
        float* t = in; in = ob; ob = t;
    }
    __syncthreads();
    for (int i = tid; i < CLS * D_DIM; i += 256) out[i] = in[i];
}

// ---------------------------------------------------------------------------
// Kernel 2: bins (with degenerate-sign fix) + per-edge triplet count (fused).
// ---------------------------------------------------------------------------
__launch_bounds__(256)
__global__ void tri_bins_kernel(const float* __restrict__ pos,
                                const int* __restrict__ idx_i,
                                const int* __restrict__ idx_j,
                                const int* __restrict__ idx_k,
                                const int* __restrict__ iji,
                                int* __restrict__ bins,
                                int* __restrict__ cnt)
{
    const int t = blockIdx.x * 256 + threadIdx.x;
    if (t >= T_TRI) return;
    const int ii = idx_i[t], jj = idx_j[t], kk = idx_k[t];
    const float pix = pos[3*ii], piy = pos[3*ii+1], piz = pos[3*ii+2];
    const float jx = __fsub_rn(pos[3*jj],   pix);
    const float jy = __fsub_rn(pos[3*jj+1], piy);
    const float jz = __fsub_rn(pos[3*jj+2], piz);
    const float kx = __fsub_rn(pos[3*kk],   pix);
    const float ky = __fsub_rn(pos[3*kk+1], piy);
    const float kz = __fsub_rn(pos[3*kk+2], piz);
    const float a  = __fadd_rn(__fadd_rn(__fmul_rn(jx,kx), __fmul_rn(jy,ky)),
                               __fmul_rn(jz,kz));
    const float cx = __fsub_rn(__fmul_rn(jy,kz), __fmul_rn(jz,ky));
    const float cy = __fsub_rn(__fmul_rn(jz,kx), __fmul_rn(jx,kz));
    const float cz = __fsub_rn(__fmul_rn(jx,ky), __fmul_rn(jy,kx));
    const float ss = __fadd_rn(__fadd_rn(__fmul_rn(cx,cx), __fmul_rn(cy,cy)),
                               __fmul_rn(cz,cz));
    const float b  = __fsqrt_rn(ss);

    int bin;
    if (b == 0.0f && __float_as_uint(a) == 0x80000000u) {
        // atan2(+0, -0): IEEE pi (bin 5) vs reference SVML 0 (bin 0)
        bin = 0;
    } else {
        const float angle = (float)atan2((double)b, (double)a);
        const float c = (float)(3.1415926 / 6.0);
        const float q = __fdiv_rn(angle, c);
        bin = (int)q;
        bin = bin < 0 ? 0 : (bin > CLS - 1 ? CLS - 1 : bin);
    }
    bins[t] = bin;
    atomicAdd(&cnt[iji[t]], 1);
}

// ---------------------------------------------------------------------------
// CSR build: block-scan (3 kernels) + scatter fill
// ---------------------------------------------------------------------------
__launch_bounds__(256)
__global__ void scan1_kernel(const int* __restrict__ cnt, int* __restrict__ offs,
                             int* __restrict__ bsum)
{
    __shared__ int buf[256];
    const int i = blockIdx.x * 256 + threadIdx.x;
    const int v = (i < E_EDGES) ? cnt[i] : 0;
    buf[threadIdx.x] = v;
    __syncthreads();
    for (int o = 1; o < 256; o <<= 1) {
        const int t = (threadIdx.x >= o) ? buf[threadIdx.x - o] : 0;
        __syncthreads();
        buf[threadIdx.x] += t;
        __syncthreads();
    }
    if (i < E_EDGES) offs[i] = buf[threadIdx.x] - v;
    if (threadIdx.x == 255) bsum[blockIdx.x] = buf[255];
}

__launch_bounds__(1024)
__global__ void scan2_kernel(int* __restrict__ bsum, int nb)
{
    __shared__ int buf[1024];
    const int tid = threadIdx.x;
    const int v = (tid < nb) ? bsum[tid] : 0;
    buf[tid] = v;
    __syncthreads();
    for (int o = 1; o < 1024; o <<= 1) {
        const int t = (tid >= o) ? buf[tid - o] : 0;
        __syncthreads();
        buf[tid] += t;
        __syncthreads();
    }
    if (tid < nb) bsum[tid] = buf[tid] - v;   // exclusive
}

__launch_bounds__(256)
__global__ void scan3_kernel(int* __restrict__ offs, const int* __restrict__ bsum)
{
    const int i = blockIdx.x * 256 + threadIdx.x;
    if (i < E_EDGES) offs[i] += bsum[blockIdx.x];
}

__launch_bounds__(256)
__global__ void fill_kernel(const int* __restrict__ iji, const int* __restrict__ offs,
                            int* __restrict__ cur, int* __restrict__ slot)
{
    const int t = blockIdx.x * 256 + threadIdx.x;
    if (t >= T_TRI) return;
    const int e = iji[t];
    const int p = offs[e] + atomicAdd(&cur[e], 1);
    slot[p] = t;
}

// ---------------------------------------------------------------------------
// Kernel 3: projection GEMM  C_bf16[M,128] = A[M,128] @ W[128,128]
// ---------------------------------------------------------------------------
__launch_bounds__(256)
__global__ void gemm_proj_bf16(const float* __restrict__ A, const float* __restrict__ W,
                               unsigned short* __restrict__ C, int M)
{
    __shared__ float Wl[128 * 128];
    __shared__ float Al[8][128];
    for (int i = threadIdx.x * 4; i < 128 * 128; i += 1024)
        *(float4*)&Wl[i] = *(const float4*)&W[i];
    const int r  = threadIdx.x >> 5;
    const int c4 = (threadIdx.x & 31) * 4;
    const int ntiles = M / 8;
    for (int tile = blockIdx.x; tile < ntiles; tile += gridDim.x) {
        const int row0 = tile * 8;
        __syncthreads();
        for (int i = threadIdx.x; i < 8 * 128; i += 256)
            Al[i >> 7][i & 127] = A[(int64_t)(row0 + (i >> 7)) * 128 + (i & 127)];
        __syncthreads();
        float a0 = 0.f, a1 = 0.f, a2 = 0.f, a3 = 0.f;
        #pragma unroll 8
        for (int k = 0; k < 128; ++k) {
            const float av = Al[r][k];
            const float4 w = *(const float4*)&Wl[k * 128 + c4];
            a0 += av * w.x; a1 += av * w.y; a2 += av * w.z; a3 += av * w.w;
        }
        ushort4 o;
        o.x = f2bf(a0); o.y = f2bf(a1); o.z = f2bf(a2); o.w = f2bf(a3);
        *(ushort4*)&C[(int64_t)(row0 + r) * 128 + c4] = o;
    }
}

// ---------------------------------------------------------------------------
// Kernel 4: FUSED per-edge attention + aggregation + he + LN1.
// One wave (64 lanes) per edge; lane owns dims 2*lane, 2*lane+1; lanes
// [8h, 8h+8) form head h.  CSR triplet list -> register accumulation,
// NO atomics.  Writes he (for residual) and h = LN1(he).
// ---------------------------------------------------------------------------
__launch_bounds__(256)
__global__ void edge_att_kernel(const unsigned short* __restrict__ Kh,
                                const unsigned short* __restrict__ Qh,
                                const unsigned short* __restrict__ Vh,
                                const float* __restrict__ aeT,
                                const int* __restrict__ bins,
                                const int* __restrict__ ikj,
                                const int* __restrict__ slot,
                                const int* __restrict__ offs,
                                const int* __restrict__ cnt,
                                const float* __restrict__ battn,
                                const float* __restrict__ disW,
                                const float* __restrict__ bond,
                                const float* __restrict__ g1,
                                const float* __restrict__ b1,
                                float* __restrict__ he,
                                float* __restrict__ hout)
{
    __shared__ float aeL[CLS * D_DIM];
    for (int i = threadIdx.x; i < CLS * D_DIM; i += 256) aeL[i] = aeT[i];
    __syncthreads();
    const int wid  = threadIdx.x >> 6;
    const int lane = threadIdx.x & 63;
    const int e = blockIdx.x * 4 + wid;          // E divisible by 4
    const int d0 = lane * 2;
    const int h  = lane >> 3;
    const float dw = disW[h];

    unsigned qw = *(const unsigned*)&Qh[(int64_t)e * D_DIM + d0];
    float q0, q1; bf2x(qw, q0, q1);

    float acc0 = 0.f, acc1 = 0.f, den = 0.f;
    const int start = offs[e], n = cnt[e];
    for (int s = 0; s < n; ++s) {
        const int t   = slot[start + s];
        const int ekj = ikj[t];
        const int bin = bins[t];
        const float ae0 = aeL[bin * D_DIM + d0];
        const float ae1 = aeL[bin * D_DIM + d0 + 1];
        unsigned kw = *(const unsigned*)&Kh[(int64_t)ekj * D_DIM + d0];
        float k0, k1; bf2x(kw, k0, k1);
        float pd = (k0 + ae0) * (q0 + ae0) + (k1 + ae1) * (q1 + ae1);
        pd += __shfl_xor(pd, 1);
        pd += __shfl_xor(pd, 2);
        pd += __shfl_xor(pd, 4);                 // 8-lane head dot
        const float ex = expf(pd * 0.25f + battn[ekj] * dw);
        den += ex;
        unsigned vw = *(const unsigned*)&Vh[(int64_t)ekj * D_DIM + d0];
        float v0, v1; bf2x(vw, v0, v1);
        acc0 += ex * (v0 + ae0);
        acc1 += ex * (v1 + ae1);
    }
    const float inv = (den > 0.f) ? 1.f / den : 0.f;
    const int64_t base = (int64_t)e * D_DIM;
    const float x0 = acc0 * inv + bond[base + d0];
    const float x1 = acc1 * inv + bond[base + d0 + 1];
    he[base + d0]     = x0;
    he[base + d0 + 1] = x1;
    float sum = x0 + x1;
    #pragma unroll
    for (int o = 32; o > 0; o >>= 1) sum += __shfl_xor(sum, o);
    const float mean = sum * (1.f / 128.f);
    const float dx0 = x0 - mean, dx1 = x1 - mean;
    float var = dx0 * dx0 + dx1 * dx1;
    #pragma unroll
    for (int o = 32; o > 0; o >>= 1) var += __shfl_xor(var, o);
    const float rs = rsqrtf(var * (1.f / 128.f) + 1e-5f);
    hout[base + d0]     = dx0 * rs * g1[d0]     + b1[d0];
    hout[base + d0 + 1] = dx1 * rs * g1[d0 + 1] + b1[d0 + 1];
}

// ---------------------------------------------------------------------------
// Kernel 5: fused FFN + residual + LN2 -> d_out.
// ---------------------------------------------------------------------------
__launch_bounds__(256)
__global__ void ffn_ln2_kernel(const float* __restrict__ hin,
                               const float* __restrict__ he,
                               const float* __restrict__ W1,
                               const float* __restrict__ W2,
                               const float* __restrict__ g2, const float* __restrict__ b2,
                               float* __restrict__ outp)
{
    __shared__ float hs[16][132];
    __shared__ float W1c[128][64];
    __shared__ float W2c[64][128];
    __shared__ float mid[16][68];
    const int tid = threadIdx.x;
    const int r = tid >> 4;
    const int q = tid & 15;
    const int row = blockIdx.x * 16 + r;

    {
        const int li = tid * 8;
        const int lr = li >> 7, lc = li & 127;
        const float4 v0 = *(const float4*)&hin[(int64_t)(blockIdx.x * 16 + lr) * 128 + lc];
        const float4 v1 = *(const float4*)&hin[(int64_t)(blockIdx.x * 16 + lr) * 128 + lc + 4];
        hs[lr][lc+0] = v0.x; hs[lr][lc+1] = v0.y; hs[lr][lc+2] = v0.z; hs[lr][lc+3] = v0.w;
        hs[lr][lc+4] = v1.x; hs[lr][lc+5] = v1.y; hs[lr][lc+6] = v1.z; hs[lr][lc+7] = v1.w;
    }

    float acc[8] = {0.f,0.f,0.f,0.f,0.f,0.f,0.f,0.f};
    for (int c = 0; c < 4; ++c) {
        __syncthreads();
        for (int i = tid * 4; i < 8192; i += 1024) {
            const int k = i >> 6, m = i & 63;
            *(float4*)&W1c[k][m] = *(const float4*)&W1[k * 256 + c * 64 + m];
        }
        for (int i = tid * 4; i < 8192; i += 1024)
            *(float4*)&W2c[0][i] = *(const float4*)&W2[c * 8192 + i];
        __syncthreads();
        float s0 = 0.f, s1 = 0.f, s2 = 0.f, s3 = 0.f;
        #pragma unroll 8
        for (int k = 0; k < 128; ++k) {
            const float hv = hs[r][k];
            const float4 w = *(const float4*)&W1c[k][q * 4];
            s0 += hv * w.x; s1 += hv * w.y; s2 += hv * w.z; s3 += hv * w.w;
        }
        mid[r][q*4+0] = fmaxf(s0, 0.f);
        mid[r][q*4+1] = fmaxf(s1, 0.f);
        mid[r][q*4+2] = fmaxf(s2, 0.f);
        mid[r][q*4+3] = fmaxf(s3, 0.f);
        __syncthreads();
        #pragma unroll 8
        for (int m = 0; m < 64; ++m) {
            const float mv = mid[r][m];
            const float4 w0 = *(const float4*)&W2c[m][q * 8];
            const float4 w1 = *(const float4*)&W2c[m][q * 8 + 4];
            acc[0] += mv * w0.x; acc[1] += mv * w0.y; acc[2] += mv * w0.z; acc[3] += mv * w0.w;
            acc[4] += mv * w1.x; acc[5] += mv * w1.y; acc[6] += mv * w1.z; acc[7] += mv * w1.w;
        }
    }

    const int64_t ob = (int64_t)row * 128;
    const float4 h0 = *(const float4*)&he[ob + q * 8];
    const float4 h1 = *(const float4*)&he[ob + q * 8 + 4];
    float x0 = acc[0] + h0.x, x1 = acc[1] + h0.y, x2 = acc[2] + h0.z, x3 = acc[3] + h0.w;
    float x4 = acc[4] + h1.x, x5 = acc[5] + h1.y, x6 = acc[6] + h1.z, x7 = acc[7] + h1.w;
    float s = x0 + x1 + x2 + x3 + x4 + x5 + x6 + x7;
    #pragma unroll
    for (int o = 8; o > 0; o >>= 1) s += __shfl_xor(s, o);
    const float mean = s * (1.f / 128.f);
    float v = (x0-mean)*(x0-mean) + (x1-mean)*(x1-mean) + (x2-mean)*(x2-mean) + (x3-mean)*(x3-mean)
            + (x4-mean)*(x4-mean) + (x5-mean)*(x5-mean) + (x6-mean)*(x6-mean) + (x7-mean)*(x7-mean);
    #pragma unroll
    for (int o = 8; o > 0; o >>= 1) v += __shfl_xor(v, o);
    const float rs = rsqrtf(v * (1.f / 128.f) + 1e-5f);
    const int fb = q * 8;
    float4 o0, o1;
    o0.x = (x0-mean)*rs*g2[fb+0] + b2[fb+0];
    o0.y = (x1-mean)*rs*g2[fb+1] + b2[fb+1];
    o0.z = (x2-mean)*rs*g2[fb+2] + b2[fb+2];
    o0.w = (x3-mean)*rs*g2[fb+3] + b2[fb+3];
    o1.x = (x4-mean)*rs*g2[fb+4] + b2[fb+4];
    o1.y = (x5-mean)*rs*g2[fb+5] + b2[fb+5];
    o1.z = (x6-mean)*rs*g2[fb+6] + b2[fb+6];
    o1.w = (x7-mean)*rs*g2[fb+7] + b2[fb+7];
    *(float4*)&outp[ob + q * 8]     = o0;
    *(float4*)&outp[ob + q * 8 + 4] = o1;
}

// ---------------------------------------------------------------------------
extern "C" void kernel_launch(void* const* d_in, const int* in_sizes, int n_in,
                              void* d_out, int out_size, void* d_ws, size_t ws_size,
                              hipStream_t stream)
{
    const float* bond     = (const float*)d_in[0];
    const float* pos      = (const float*)d_in[1];
    const float* battn    = (const float*)d_in[2];
    const float* ang_tab  = (const float*)d_in[3];
    const float* ang_in_W = (const float*)d_in[4];
    const float* ang_in_b = (const float*)d_in[5];
    const float* ang2_W   = (const float*)d_in[6];
    const float* ang2_b   = (const float*)d_in[7];
    const float* ang1_W   = (const float*)d_in[8];
    const float* ang1_b   = (const float*)d_in[9];
    const float* k_W      = (const float*)d_in[10];
    const float* q_W      = (const float*)d_in[11];
    const float* v_W      = (const float*)d_in[12];
    const float* dis_W    = (const float*)d_in[13];
    const float* ffn_W1   = (const float*)d_in[14];
    const float* ffn_W2   = (const float*)d_in[15];
    const float* ln1_g    = (const float*)d_in[16];
    const float* ln1_b    = (const float*)d_in[17];
    const float* ln2_g    = (const float*)d_in[18];
    const float* ln2_b    = (const float*)d_in[19];
    const int*   index_kj = (const int*)d_in[20];
    const int*   index_ji = (const int*)d_in[21];
    const int*   idx_i    = (const int*)d_in[22];
    const int*   idx_j    = (const int*)d_in[23];
    const int*   idx_k    = (const int*)d_in[24];

    float* ws = (float*)d_ws;
    // ws layout (float offsets) — ~262 MB, no overlaps
    int*            bins  = (int*)(ws + 0);          //   400,000
    int*            slot  = (int*)(ws + 400000);     //   400,000
    int*            offs  = (int*)(ws + 800000);     //   200,000
    int*            cnt   = (int*)(ws + 1000000);    //   200,000
    int*            cur   = (int*)(ws + 1200000);    //   200,000
    int*            bsum  = (int*)(ws + 1400000);    //     1,024
    float*          aeT   = ws + 1401088;            //       768
    float*          heb   = ws + 1401856;            // 25,600,000
    float*          hb    = ws + 27001856;           // 25,600,000
    unsigned short* Vh    = (unsigned short*)(ws + 52601856);   // 25,600,000 bf16

    // d_out doubles as K/Q bf16 storage, then final out
    unsigned short* Kh = (unsigned short*)d_out;
    unsigned short* Qh = Kh + 25600000;
    float*          out = (float*)d_out;

    hipMemsetAsync(cnt, 0, (size_t)E_EDGES * sizeof(int), stream);
    hipMemsetAsync(cur, 0, (size_t)E_EDGES * sizeof(int), stream);

    ang_mlp_kernel<<<1, 256, 0, stream>>>(ang_tab, ang_in_W, ang_in_b,
                                          ang2_W, ang2_b, ang1_W, ang1_b, aeT);
    tri_bins_kernel<<<(T_TRI + 255) / 256, 256, 0, stream>>>(
        pos, idx_i, idx_j, idx_k, index_ji, bins, cnt);

    const int NB = (E_EDGES + 255) / 256;    // 782
    scan1_kernel<<<NB, 256, 0, stream>>>(cnt, offs, bsum);
    scan2_kernel<<<1, 1024, 0, stream>>>(bsum, NB);
    scan3_kernel<<<NB, 256, 0, stream>>>(offs, bsum);
    fill_kernel<<<(T_TRI + 255) / 256, 256, 0, stream>>>(index_ji, offs, cur, slot);

    gemm_proj_bf16<<<512, 256, 0, stream>>>(bond, k_W, Kh, E_EDGES);
    gemm_proj_bf16<<<512, 256, 0, stream>>>(bond, q_W, Qh, E_EDGES);
    gemm_proj_bf16<<<512, 256, 0, stream>>>(bond, v_W, Vh, E_EDGES);

    edge_att_kernel<<<E_EDGES / 4, 256, 0, stream>>>(
        Kh, Qh, Vh, aeT, bins, index_kj, slot, offs, cnt,
        battn, dis_W, bond, ln1_g, ln1_b, heb, hb);

    ffn_ln2_kernel<<<E_EDGES / 16, 256, 0, stream>>>(hb, heb, ffn_W1, ffn_W2,
                                                     ln2_g, ln2_b, out);
}

// Round 18
// 1116.743 us; speedup vs baseline: 4.0721x; 1.4563x over previous
//
#include <hip/hip_runtime.h>
#include <cstdint>
#include <math.h>

// Problem constants (match reference)
#define N_ATOMS 30000
#define E_EDGES 200000
#define T_TRI   400000
#define D_DIM   128
#define H_HEADS 8
#define F_FEAT  16
#define CLS     6

typedef __attribute__((ext_vector_type(8))) short bf16x8;
typedef __attribute__((ext_vector_type(4))) float f32x4;

// bf16 helpers (RNE pack, bit-shift unpack)
static __device__ __forceinline__ unsigned short f2bf(float f) {
    union { float f; unsigned u; } v; v.f = f;
    unsigned r = v.u + 0x7FFFu + ((v.u >> 16) & 1u);
    return (unsigned short)(r >> 16);
}
static __device__ __forceinline__ void bf2x(unsigned u, float& a, float& b) {
    union { unsigned u; float f; } x, y;
    x.u = u << 16; y.u = u & 0xFFFF0000u;
    a = x.f; b = y.f;
}

// ---------------------------------------------------------------------------
// Kernel 1: 6-row angle MLP -> ae_table[6][128]
// ---------------------------------------------------------------------------
__launch_bounds__(256)
__global__ void ang_mlp_kernel(const float* __restrict__ tab,
                               const float* __restrict__ W0, const float* __restrict__ b0,
                               const float* __restrict__ W1, const float* __restrict__ b1,
                               const float* __restrict__ W2, const float* __restrict__ b2,
                               float* __restrict__ out)
{
    __shared__ float bufA[CLS * D_DIM];
    __shared__ float bufB[CLS * D_DIM];
    __shared__ float Wl[D_DIM * D_DIM];
    const int tid = threadIdx.x;
    for (int i = tid; i < CLS * D_DIM; i += 256) bufA[i] = tab[i];
    const float* Ws[3] = {W0, W1, W2};
    const float* bs[3] = {b0, b1, b2};
    float* in  = bufA;
    float* ob  = bufB;
    for (int l = 0; l < 3; ++l) {
        __syncthreads();
        for (int i = tid * 4; i < D_DIM * D_DIM; i += 256 * 4)
            *(float4*)&Wl[i] = *(const float4*)&Ws[l][i];
        __syncthreads();
        for (int o = tid; o < CLS * D_DIM; o += 256) {
            const int r = o >> 7, c = o & 127;
            float acc = bs[l][c];
            #pragma unroll 8
            for (int k = 0; k < D_DIM; ++k) acc += in[r * D_DIM + k] * Wl[k * D_DIM + c];
            ob[o] = fmaxf(acc, 0.f);
        }
        float* t = in; in = ob; ob = t;
    }
    __syncthreads();
    for (int i = tid; i < CLS * D_DIM; i += 256) out[i] = in[i];
}

// ---------------------------------------------------------------------------
// Kernel 2: bins (with atan2(+0,-0) degenerate-sign fix) + per-edge count.
// ---------------------------------------------------------------------------
__launch_bounds__(256)
__global__ void tri_bins_kernel(const float* __restrict__ pos,
                                const int* __restrict__ idx_i,
                                const int* __restrict__ idx_j,
                                const int* __restrict__ idx_k,
                                const int* __restrict__ iji,
                                int* __restrict__ bins,
                                int* __restrict__ cnt)
{
    const int t = blockIdx.x * 256 + threadIdx.x;
    if (t >= T_TRI) return;
    const int ii = idx_i[t], jj = idx_j[t], kk = idx_k[t];
    const float pix = pos[3*ii], piy = pos[3*ii+1], piz = pos[3*ii+2];
    const float jx = __fsub_rn(pos[3*jj],   pix);
    const float jy = __fsub_rn(pos[3*jj+1], piy);
    const float jz = __fsub_rn(pos[3*jj+2], piz);
    const float kx = __fsub_rn(pos[3*kk],   pix);
    const float ky = __fsub_rn(pos[3*kk+1], piy);
    const float kz = __fsub_rn(pos[3*kk+2], piz);
    const float a  = __fadd_rn(__fadd_rn(__fmul_rn(jx,kx), __fmul_rn(jy,ky)),
                               __fmul_rn(jz,kz));
    const float cx = __fsub_rn(__fmul_rn(jy,kz), __fmul_rn(jz,ky));
    const float cy = __fsub_rn(__fmul_rn(jz,kx), __fmul_rn(jx,kz));
    const float cz = __fsub_rn(__fmul_rn(jx,ky), __fmul_rn(jy,kx));
    const float ss = __fadd_rn(__fadd_rn(__fmul_rn(cx,cx), __fmul_rn(cy,cy)),
                               __fmul_rn(cz,cz));
    const float b  = __fsqrt_rn(ss);

    int bin;
    if (b == 0.0f && __float_as_uint(a) == 0x80000000u) {
        bin = 0;   // atan2(+0,-0): IEEE pi (bin 5) vs reference SVML 0 (bin 0)
    } else {
        const float angle = (float)atan2((double)b, (double)a);
        const float c = (float)(3.1415926 / 6.0);
        const float q = __fdiv_rn(angle, c);
        bin = (int)q;
        bin = bin < 0 ? 0 : (bin > CLS - 1 ? CLS - 1 : bin);
    }
    bins[t] = bin;
    atomicAdd(&cnt[iji[t]], 1);
}

// ---------------------------------------------------------------------------
// CSR build: block-scan (3 kernels) + scatter fill
// ---------------------------------------------------------------------------
__launch_bounds__(256)
__global__ void scan1_kernel(const int* __restrict__ cnt, int* __restrict__ offs,
                             int* __restrict__ bsum)
{
    __shared__ int buf[256];
    const int i = blockIdx.x * 256 + threadIdx.x;
    const int v = (i < E_EDGES) ? cnt[i] : 0;
    buf[threadIdx.x] = v;
    __syncthreads();
    for (int o = 1; o < 256; o <<= 1) {
        const int t = (threadIdx.x >= o) ? buf[threadIdx.x - o] : 0;
        __syncthreads();
        buf[threadIdx.x] += t;
        __syncthreads();
    }
    if (i < E_EDGES) offs[i] = buf[threadIdx.x] - v;
    if (threadIdx.x == 255) bsum[blockIdx.x] = buf[255];
}

__launch_bounds__(1024)
__global__ void scan2_kernel(int* __restrict__ bsum, int nb)
{
    __shared__ int buf[1024];
    const int tid = threadIdx.x;
    const int v = (tid < nb) ? bsum[tid] : 0;
    buf[tid] = v;
    __syncthreads();
    for (int o = 1; o < 1024; o <<= 1) {
        const int t = (tid >= o) ? buf[tid - o] : 0;
        __syncthreads();
        buf[tid] += t;
        __syncthreads();
    }
    if (tid < nb) bsum[tid] = buf[tid] - v;   // exclusive
}

__launch_bounds__(256)
__global__ void scan3_kernel(int* __restrict__ offs, const int* __restrict__ bsum)
{
    const int i = blockIdx.x * 256 + threadIdx.x;
    if (i < E_EDGES) offs[i] += bsum[blockIdx.x];
}

__launch_bounds__(256)
__global__ void fill_kernel(const int* __restrict__ iji, const int* __restrict__ offs,
                            int* __restrict__ cur, int* __restrict__ slot)
{
    const int t = blockIdx.x * 256 + threadIdx.x;
    if (t >= T_TRI) return;
    const int e = iji[t];
    const int p = offs[e] + atomicAdd(&cur[e], 1);
    slot[p] = t;
}

// ---------------------------------------------------------------------------
// Kernel 3: projection GEMM  C_bf16[M,128] = A[M,128] @ W[128,128]  (fp32)
// ---------------------------------------------------------------------------
__launch_bounds__(256)
__global__ void gemm_proj_bf16(const float* __restrict__ A, const float* __restrict__ W,
                               unsigned short* __restrict__ C, int M)
{
    __shared__ float Wl[128 * 128];
    __shared__ float Al[8][128];
    for (int i = threadIdx.x * 4; i < 128 * 128; i += 1024)
        *(float4*)&Wl[i] = *(const float4*)&W[i];
    const int r  = threadIdx.x >> 5;
    const int c4 = (threadIdx.x & 31) * 4;
    const int ntiles = M / 8;
    for (int tile = blockIdx.x; tile < ntiles; tile += gridDim.x) {
        const int row0 = tile * 8;
        __syncthreads();
        for (int i = threadIdx.x; i < 8 * 128; i += 256)
            Al[i >> 7][i & 127] = A[(int64_t)(row0 + (i >> 7)) * 128 + (i & 127)];
        __syncthreads();
        float a0 = 0.f, a1 = 0.f, a2 = 0.f, a3 = 0.f;
        #pragma unroll 8
        for (int k = 0; k < 128; ++k) {
            const float av = Al[r][k];
            const float4 w = *(const float4*)&Wl[k * 128 + c4];
            a0 += av * w.x; a1 += av * w.y; a2 += av * w.z; a3 += av * w.w;
        }
        ushort4 o;
        o.x = f2bf(a0); o.y = f2bf(a1); o.z = f2bf(a2); o.w = f2bf(a3);
        *(ushort4*)&C[(int64_t)(row0 + r) * 128 + c4] = o;
    }
}

// ---------------------------------------------------------------------------
// Kernel 4: FUSED per-edge attention + aggregation + he + LN1 (-> bf16 h)
// ---------------------------------------------------------------------------
__launch_bounds__(256)
__global__ void edge_att_kernel(const unsigned short* __restrict__ Kh,
                                const unsigned short* __restrict__ Qh,
                                const unsigned short* __restrict__ Vh,
                                const float* __restrict__ aeT,
                                const int* __restrict__ bins,
                                const int* __restrict__ ikj,
                                const int* __restrict__ slot,
                                const int* __restrict__ offs,
                                const int* __restrict__ cnt,
                                const float* __restrict__ battn,
                                const float* __restrict__ disW,
                                const float* __restrict__ bond,
                                const float* __restrict__ g1,
                                const float* __restrict__ b1,
                                float* __restrict__ he,
                                unsigned short* __restrict__ hbf)
{
    __shared__ float aeL[CLS * D_DIM];
    for (int i = threadIdx.x; i < CLS * D_DIM; i += 256) aeL[i] = aeT[i];
    __syncthreads();
    const int wid  = threadIdx.x >> 6;
    const int lane = threadIdx.x & 63;
    const int e = blockIdx.x * 4 + wid;
    const int d0 = lane * 2;
    const int h  = lane >> 3;
    const float dw = disW[h];

    unsigned qw = *(const unsigned*)&Qh[(int64_t)e * D_DIM + d0];
    float q0, q1; bf2x(qw, q0, q1);

    float acc0 = 0.f, acc1 = 0.f, den = 0.f;
    const int start = offs[e], n = cnt[e];
    for (int s = 0; s < n; ++s) {
        const int t   = slot[start + s];
        const int ekj = ikj[t];
        const int bin = bins[t];
        const float ae0 = aeL[bin * D_DIM + d0];
        const float ae1 = aeL[bin * D_DIM + d0 + 1];
        unsigned kw = *(const unsigned*)&Kh[(int64_t)ekj * D_DIM + d0];
        float k0, k1; bf2x(kw, k0, k1);
        float pd = (k0 + ae0) * (q0 + ae0) + (k1 + ae1) * (q1 + ae1);
        pd += __shfl_xor(pd, 1);
        pd += __shfl_xor(pd, 2);
        pd += __shfl_xor(pd, 4);
        const float ex = expf(pd * 0.25f + battn[ekj] * dw);
        den += ex;
        unsigned vw = *(const unsigned*)&Vh[(int64_t)ekj * D_DIM + d0];
        float v0, v1; bf2x(vw, v0, v1);
        acc0 += ex * (v0 + ae0);
        acc1 += ex * (v1 + ae1);
    }
    const float inv = (den > 0.f) ? 1.f / den : 0.f;
    const int64_t base = (int64_t)e * D_DIM;
    const float x0 = acc0 * inv + bond[base + d0];
    const float x1 = acc1 * inv + bond[base + d0 + 1];
    he[base + d0]     = x0;
    he[base + d0 + 1] = x1;
    float sum = x0 + x1;
    #pragma unroll
    for (int o = 32; o > 0; o >>= 1) sum += __shfl_xor(sum, o);
    const float mean = sum * (1.f / 128.f);
    const float dx0 = x0 - mean, dx1 = x1 - mean;
    float var = dx0 * dx0 + dx1 * dx1;
    #pragma unroll
    for (int o = 32; o > 0; o >>= 1) var += __shfl_xor(var, o);
    const float rs = rsqrtf(var * (1.f / 128.f) + 1e-5f);
    const float h0v = dx0 * rs * g1[d0]     + b1[d0];
    const float h1v = dx1 * rs * g1[d0 + 1] + b1[d0 + 1];
    *(unsigned*)&hbf[base + d0] =
        (unsigned)f2bf(h0v) | ((unsigned)f2bf(h1v) << 16);
}

// ---------------------------------------------------------------------------
// Weight transpose+convert: W1t[256][128], W2t[128][256] in bf16
// ---------------------------------------------------------------------------
__launch_bounds__(256)
__global__ void conv_w_kernel(const float* __restrict__ W1, const float* __restrict__ W2,
                              unsigned short* __restrict__ W1t,
                              unsigned short* __restrict__ W2t)
{
    const int i = blockIdx.x * 256 + threadIdx.x;
    if (i >= 128 * 256) return;
    {   const int n = i >> 7, k = i & 127;          // W1t[n][k] = W1[k][n]
        W1t[n * 128 + k] = f2bf(W1[k * 256 + n]); }
    {   const int n = i >> 8, k = i & 255;          // W2t[n][k] = W2[k][n]
        W2t[n * 256 + k] = f2bf(W2[k * 128 + n]); }
}

// ---------------------------------------------------------------------------
// FFN GEMM1 (MFMA): mid[E,256] = relu(h @ W1), bf16 in/out, f32 accum.
// 64 rows/block, 4 waves x 16 rows; 16 n-tiles/wave; K=128 (4 steps).
// ---------------------------------------------------------------------------
__launch_bounds__(256)
__global__ void ffn1_mfma(const unsigned short* __restrict__ hbf,
                          const unsigned short* __restrict__ W1t,
                          unsigned short* __restrict__ mid)
{
    __shared__ unsigned short ms[64 * 256];
    const int lane = threadIdx.x & 63, w = threadIdx.x >> 6;
    const int m0 = blockIdx.x * 64 + w * 16;
    const int lr = lane & 15, g = lane >> 4;
    f32x4 acc[16];
    #pragma unroll
    for (int n = 0; n < 16; ++n) acc[n] = (f32x4){0.f, 0.f, 0.f, 0.f};
    for (int kk = 0; kk < 4; ++kk) {
        const bf16x8 a = *(const bf16x8*)&hbf[(int64_t)(m0 + lr) * 128 + kk * 32 + g * 8];
        #pragma unroll
        for (int n = 0; n < 16; ++n) {
            const bf16x8 b = *(const bf16x8*)&W1t[(n * 16 + lr) * 128 + kk * 32 + g * 8];
            acc[n] = __builtin_amdgcn_mfma_f32_16x16x32_bf16(a, b, acc[n], 0, 0, 0);
        }
    }
    #pragma unroll
    for (int n = 0; n < 16; ++n)
        #pragma unroll
        for (int r = 0; r < 4; ++r) {
            float v = acc[n][r];
            v = v > 0.f ? v : 0.f;
            ms[(w * 16 + g * 4 + r) * 256 + n * 16 + lr] = f2bf(v);
        }
    __syncthreads();
    const int64_t base = (int64_t)blockIdx.x * 64 * 256;
    for (int i = threadIdx.x; i < 64 * 256 / 8; i += 256)
        *(uint4*)&mid[base + (int64_t)i * 8] = *(const uint4*)&ms[i * 8];
}

// ---------------------------------------------------------------------------
// FFN GEMM2 (MFMA) + residual + LN2: out = LN2(mid @ W2 + he) -> d_out.
// 64 rows/block; C staged in LDS; per-row LN with 64-lane waves.
// ---------------------------------------------------------------------------
__launch_bounds__(256)
__global__ void ffn2_mfma(const unsigned short* __restrict__ mid,
                          const unsigned short* __restrict__ W2t,
                          const float* __restrict__ he,
                          const float* __restrict__ g2, const float* __restrict__ b2,
                          float* __restrict__ outp)
{
    __shared__ float cs[64][132];
    const int lane = threadIdx.x & 63, w = threadIdx.x >> 6;
    const int m0 = blockIdx.x * 64 + w * 16;
    const int lr = lane & 15, g = lane >> 4;
    f32x4 acc[8];
    #pragma unroll
    for (int n = 0; n < 8; ++n) acc[n] = (f32x4){0.f, 0.f, 0.f, 0.f};
    for (int kk = 0; kk < 8; ++kk) {
        const bf16x8 a = *(const bf16x8*)&mid[(int64_t)(m0 + lr) * 256 + kk * 32 + g * 8];
        #pragma unroll
        for (int n = 0; n < 8; ++n) {
            const bf16x8 b = *(const bf16x8*)&W2t[(n * 16 + lr) * 256 + kk * 32 + g * 8];
            acc[n] = __builtin_amdgcn_mfma_f32_16x16x32_bf16(a, b, acc[n], 0, 0, 0);
        }
    }
    #pragma unroll
    for (int n = 0; n < 8; ++n)
        #pragma unroll
        for (int r = 0; r < 4; ++r)
            cs[w * 16 + g * 4 + r][n * 16 + lr] = acc[n][r];
    __syncthreads();
    for (int i = 0; i < 16; ++i) {
        const int row = w * 16 + i;
        const int64_t rg = (int64_t)(blockIdx.x * 64 + row) * 128;
        float x0 = cs[row][lane]      + he[rg + lane];
        float x1 = cs[row][64 + lane] + he[rg + 64 + lane];
        float s = x0 + x1;
        #pragma unroll
        for (int o = 32; o > 0; o >>= 1) s += __shfl_xor(s, o);
        const float mean = s * (1.f / 128.f);
        const float d0 = x0 - mean, d1 = x1 - mean;
        float v = d0 * d0 + d1 * d1;
        #pragma unroll
        for (int o = 32; o > 0; o >>= 1) v += __shfl_xor(v, o);
        const float rs = rsqrtf(v * (1.f / 128.f) + 1e-5f);
        outp[rg + lane]      = d0 * rs * g2[lane]      + b2[lane];
        outp[rg + 64 + lane] = d1 * rs * g2[lane + 64] + b2[lane + 64];
    }
}

// ---------------------------------------------------------------------------
extern "C" void kernel_launch(void* const* d_in, const int* in_sizes, int n_in,
                              void* d_out, int out_size, void* d_ws, size_t ws_size,
                              hipStream_t stream)
{
    const float* bond     = (const float*)d_in[0];
    const float* pos      = (const float*)d_in[1];
    const float* battn    = (const float*)d_in[2];
    const float* ang_tab  = (const float*)d_in[3];
    const float* ang_in_W = (const float*)d_in[4];
    const float* ang_in_b = (const float*)d_in[5];
    const float* ang2_W   = (const float*)d_in[6];
    const float* ang2_b   = (const float*)d_in[7];
    const float* ang1_W   = (const float*)d_in[8];
    const float* ang1_b   = (const float*)d_in[9];
    const float* k_W      = (const float*)d_in[10];
    const float* q_W      = (const float*)d_in[11];
    const float* v_W      = (const float*)d_in[12];
    const float* dis_W    = (const float*)d_in[13];
    const float* ffn_W1   = (const float*)d_in[14];
    const float* ffn_W2   = (const float*)d_in[15];
    const float* ln1_g    = (const float*)d_in[16];
    const float* ln1_b    = (const float*)d_in[17];
    const float* ln2_g    = (const float*)d_in[18];
    const float* ln2_b    = (const float*)d_in[19];
    const int*   index_kj = (const int*)d_in[20];
    const int*   index_ji = (const int*)d_in[21];
    const int*   idx_i    = (const int*)d_in[22];
    const int*   idx_j    = (const int*)d_in[23];
    const int*   idx_k    = (const int*)d_in[24];

    float* ws = (float*)d_ws;
    // ws layout (float offsets) — ~313 MB, no overlaps
    int*            bins  = (int*)(ws + 0);          //   400,000
    int*            slot  = (int*)(ws + 400000);     //   400,000
    int*            offs  = (int*)(ws + 800000);     //   200,000
    int*            cnt   = (int*)(ws + 1000000);    //   200,000
    int*            cur   = (int*)(ws + 1200000);    //   200,000
    int*            bsum  = (int*)(ws + 1400000);    //     1,024
    float*          aeT   = ws + 1401088;            //       768
    unsigned short* W1t   = (unsigned short*)(ws + 1401856);   // 32,768 us
    unsigned short* W2t   = (unsigned short*)(ws + 1418240);   // 32,768 us
    float*          heb   = ws + 1434624;            // 25,600,000
    unsigned short* hbf   = (unsigned short*)(ws + 27034624); // 25.6M us
    unsigned short* Vh    = (unsigned short*)(ws + 39834624); // 25.6M us
    unsigned short* mid   = (unsigned short*)(ws + 52634624); // 51.2M us -> ends 78,234,624

    // d_out doubles as K/Q bf16 storage, then final out
    unsigned short* Kh = (unsigned short*)d_out;
    unsigned short* Qh = Kh + 25600000;
    float*          out = (float*)d_out;

    hipMemsetAsync(cnt, 0, (size_t)E_EDGES * sizeof(int), stream);
    hipMemsetAsync(cur, 0, (size_t)E_EDGES * sizeof(int), stream);

    ang_mlp_kernel<<<1, 256, 0, stream>>>(ang_tab, ang_in_W, ang_in_b,
                                          ang2_W, ang2_b, ang1_W, ang1_b, aeT);
    conv_w_kernel<<<128, 256, 0, stream>>>(ffn_W1, ffn_W2, W1t, W2t);
    tri_bins_kernel<<<(T_TRI + 255) / 256, 256, 0, stream>>>(
        pos, idx_i, idx_j, idx_k, index_ji, bins, cnt);

    const int NB = (E_EDGES + 255) / 256;    // 782
    scan1_kernel<<<NB, 256, 0, stream>>>(cnt, offs, bsum);
    scan2_kernel<<<1, 1024, 0, stream>>>(bsum, NB);
    scan3_kernel<<<NB, 256, 0, stream>>>(offs, bsum);
    fill_kernel<<<(T_TRI + 255) / 256, 256, 0, stream>>>(index_ji, offs, cur, slot);

    gemm_proj_bf16<<<512, 256, 0, stream>>>(bond, k_W, Kh, E_EDGES);
    gemm_proj_bf16<<<512, 256, 0, stream>>>(bond, q_W, Qh, E_EDGES);
    gemm_proj_bf16<<<512, 256, 0, stream>>>(bond, v_W, Vh, E_EDGES);

    edge_att_kernel<<<E_EDGES / 4, 256, 0, stream>>>(
        Kh, Qh, Vh, aeT, bins, index_kj, slot, offs, cnt,
        battn, dis_W, bond, ln1_g, ln1_b, heb, hbf);

    ffn1_mfma<<<E_EDGES / 64, 256, 0, stream>>>(hbf, W1t, mid);
    ffn2_mfma<<<E_EDGES / 64, 256, 0, stream>>>(mid, W2t, heb, ln2_g, ln2_b, out);
}

// Round 19
// 775.912 us; speedup vs baseline: 5.8609x; 1.4393x over previous
//
#include <hip/hip_runtime.h>
#include <cstdint>
#include <math.h>

// Problem constants (match reference)
#define N_ATOMS 30000
#define E_EDGES 200000
#define T_TRI   400000
#define D_DIM   128
#define H_HEADS 8
#define F_FEAT  16
#define CLS     6

typedef __attribute__((ext_vector_type(8))) short bf16x8;
typedef __attribute__((ext_vector_type(4))) float f32x4;

// bf16 helpers (RNE pack, bit-shift unpack)
static __device__ __forceinline__ unsigned short f2bf(float f) {
    union { float f; unsigned u; } v; v.f = f;
    unsigned r = v.u + 0x7FFFu + ((v.u >> 16) & 1u);
    return (unsigned short)(r >> 16);
}
static __device__ __forceinline__ void bf2x(unsigned u, float& a, float& b) {
    union { unsigned u; float f; } x, y;
    x.u = u << 16; y.u = u & 0xFFFF0000u;
    a = x.f; b = y.f;
}

// ---------------------------------------------------------------------------
// Kernel 1: 6-row angle MLP -> ae_table[6][128]
// ---------------------------------------------------------------------------
__launch_bounds__(256)
__global__ void ang_mlp_kernel(const float* __restrict__ tab,
                               const float* __restrict__ W0, const float* __restrict__ b0,
                               const float* __restrict__ W1, const float* __restrict__ b1,
                               const float* __restrict__ W2, const float* __restrict__ b2,
                               float* __restrict__ out)
{
    __shared__ float bufA[CLS * D_DIM];
    __shared__ float bufB[CLS * D_DIM];
    __shared__ float Wl[D_DIM * D_DIM];
    const int tid = threadIdx.x;
    for (int i = tid; i < CLS * D_DIM; i += 256) bufA[i] = tab[i];
    const float* Ws[3] = {W0, W1, W2};
    const float* bs[3] = {b0, b1, b2};
    float* in  = bufA;
    float* ob  = bufB;
    for (int l = 0; l < 3; ++l) {
        __syncthreads();
        for (int i = tid * 4; i < D_DIM * D_DIM; i += 256 * 4)
            *(float4*)&Wl[i] = *(const float4*)&Ws[l][i];
        __syncthreads();
        for (int o = tid; o < CLS * D_DIM; o += 256) {
            const int r = o >> 7, c = o & 127;
            float acc = bs[l][c];
            #pragma unroll 8
            for (int k = 0; k < D_DIM; ++k) acc += in[r * D_DIM + k] * Wl[k * D_DIM + c];
            ob[o] = fmaxf(acc, 0.f);
        }
        float* t = in; in = ob; ob = t;
    }
    __syncthreads();
    for (int i = tid; i < CLS * D_DIM; i += 256) out[i] = in[i];
}

// ---------------------------------------------------------------------------
// Kernel 2: bins (with atan2(+0,-0) degenerate-sign fix) + per-edge count.
// ---------------------------------------------------------------------------
__launch_bounds__(256)
__global__ void tri_bins_kernel(const float* __restrict__ pos,
                                const int* __restrict__ idx_i,
                                const int* __restrict__ idx_j,
                                const int* __restrict__ idx_k,
                                const int* __restrict__ iji,
                                int* __restrict__ bins,
                                int* __restrict__ cnt)
{
    const int t = blockIdx.x * 256 + threadIdx.x;
    if (t >= T_TRI) return;
    const int ii = idx_i[t], jj = idx_j[t], kk = idx_k[t];
    const float pix = pos[3*ii], piy = pos[3*ii+1], piz = pos[3*ii+2];
    const float jx = __fsub_rn(pos[3*jj],   pix);
    const float jy = __fsub_rn(pos[3*jj+1], piy);
    const float jz = __fsub_rn(pos[3*jj+2], piz);
    const float kx = __fsub_rn(pos[3*kk],   pix);
    const float ky = __fsub_rn(pos[3*kk+1], piy);
    const float kz = __fsub_rn(pos[3*kk+2], piz);
    const float a  = __fadd_rn(__fadd_rn(__fmul_rn(jx,kx), __fmul_rn(jy,ky)),
                               __fmul_rn(jz,kz));
    const float cx = __fsub_rn(__fmul_rn(jy,kz), __fmul_rn(jz,ky));
    const float cy = __fsub_rn(__fmul_rn(jz,kx), __fmul_rn(jx,kz));
    const float cz = __fsub_rn(__fmul_rn(jx,ky), __fmul_rn(jy,kx));
    const float ss = __fadd_rn(__fadd_rn(__fmul_rn(cx,cx), __fmul_rn(cy,cy)),
                               __fmul_rn(cz,cz));
    const float b  = __fsqrt_rn(ss);

    int bin;
    if (b == 0.0f && __float_as_uint(a) == 0x80000000u) {
        bin = 0;   // atan2(+0,-0): IEEE pi (bin 5) vs reference SVML 0 (bin 0)
    } else {
        const float angle = (float)atan2((double)b, (double)a);
        const float c = (float)(3.1415926 / 6.0);
        const float q = __fdiv_rn(angle, c);
        bin = (int)q;
        bin = bin < 0 ? 0 : (bin > CLS - 1 ? CLS - 1 : bin);
    }
    bins[t] = bin;
    atomicAdd(&cnt[iji[t]], 1);
}

// ---------------------------------------------------------------------------
// CSR build: block-scan (3 kernels) + scatter fill
// ---------------------------------------------------------------------------
__launch_bounds__(256)
__global__ void scan1_kernel(const int* __restrict__ cnt, int* __restrict__ offs,
                             int* __restrict__ bsum)
{
    __shared__ int buf[256];
    const int i = blockIdx.x * 256 + threadIdx.x;
    const int v = (i < E_EDGES) ? cnt[i] : 0;
    buf[threadIdx.x] = v;
    __syncthreads();
    for (int o = 1; o < 256; o <<= 1) {
        const int t = (threadIdx.x >= o) ? buf[threadIdx.x - o] : 0;
        __syncthreads();
        buf[threadIdx.x] += t;
        __syncthreads();
    }
    if (i < E_EDGES) offs[i] = buf[threadIdx.x] - v;
    if (threadIdx.x == 255) bsum[blockIdx.x] = buf[255];
}

__launch_bounds__(1024)
__global__ void scan2_kernel(int* __restrict__ bsum, int nb)
{
    __shared__ int buf[1024];
    const int tid = threadIdx.x;
    const int v = (tid < nb) ? bsum[tid] : 0;
    buf[tid] = v;
    __syncthreads();
    for (int o = 1; o < 1024; o <<= 1) {
        const int t = (tid >= o) ? buf[tid - o] : 0;
        __syncthreads();
        buf[tid] += t;
        __syncthreads();
    }
    if (tid < nb) bsum[tid] = buf[tid] - v;   // exclusive
}

__launch_bounds__(256)
__global__ void scan3_kernel(int* __restrict__ offs, const int* __restrict__ bsum)
{
    const int i = blockIdx.x * 256 + threadIdx.x;
    if (i < E_EDGES) offs[i] += bsum[blockIdx.x];
}

__launch_bounds__(256)
__global__ void fill_kernel(const int* __restrict__ iji, const int* __restrict__ offs,
                            int* __restrict__ cur, int* __restrict__ slot)
{
    const int t = blockIdx.x * 256 + threadIdx.x;
    if (t >= T_TRI) return;
    const int e = iji[t];
    const int p = offs[e] + atomicAdd(&cur[e], 1);
    slot[p] = t;
}

// ---------------------------------------------------------------------------
// bond f32 -> bf16 (each thread 8 values)
// ---------------------------------------------------------------------------
__launch_bounds__(256)
__global__ void conv_bond_kernel(const float* __restrict__ bond,
                                 unsigned short* __restrict__ bondh)
{
    const int i = blockIdx.x * 256 + threadIdx.x;     // i indexes groups of 8
    if (i >= E_EDGES * D_DIM / 8) return;
    const float4 v0 = *(const float4*)&bond[(int64_t)i * 8];
    const float4 v1 = *(const float4*)&bond[(int64_t)i * 8 + 4];
    ushort4 o0, o1;
    o0.x = f2bf(v0.x); o0.y = f2bf(v0.y); o0.z = f2bf(v0.z); o0.w = f2bf(v0.w);
    o1.x = f2bf(v1.x); o1.y = f2bf(v1.y); o1.z = f2bf(v1.z); o1.w = f2bf(v1.w);
    *(ushort4*)&bondh[(int64_t)i * 8]     = o0;
    *(ushort4*)&bondh[(int64_t)i * 8 + 4] = o1;
}

// ---------------------------------------------------------------------------
// Weight convert: Wt[384][128] = [kW|qW|vW]^T bf16;  W1t[256][128], W2t[128][256]
// ---------------------------------------------------------------------------
__launch_bounds__(256)
__global__ void conv_w_kernel(const float* __restrict__ kW, const float* __restrict__ qW,
                              const float* __restrict__ vW,
                              const float* __restrict__ W1, const float* __restrict__ W2,
                              unsigned short* __restrict__ Wt,
                              unsigned short* __restrict__ W1t,
                              unsigned short* __restrict__ W2t)
{
    const int i = blockIdx.x * 256 + threadIdx.x;
    if (i < 384 * 128) {               // Wt[n][k]
        const int n = i >> 7, k = i & 127;
        const int sel = n >> 7, c = n & 127;
        const float* W = (sel == 0) ? kW : (sel == 1) ? qW : vW;
        Wt[i] = f2bf(W[k * 128 + c]);
    }
    if (i < 128 * 256) {
        { const int n = i >> 7, k = i & 127;  W1t[n * 128 + k] = f2bf(W1[k * 256 + n]); }
        { const int n = i >> 8, k = i & 255;  W2t[n * 256 + k] = f2bf(W2[k * 128 + n]); }
    }
}

// ---------------------------------------------------------------------------
// Fused K/Q/V projection (MFMA): [Kh|Qh|Vh][E,128] = bondh @ Wt^T
// 64 rows/block, 4 waves x 16 rows; 24 n-tiles; K=128 (4 steps).
// ---------------------------------------------------------------------------
__launch_bounds__(256)
__global__ void proj_mfma(const unsigned short* __restrict__ bondh,
                          const unsigned short* __restrict__ Wt,
                          unsigned short* __restrict__ Kh,
                          unsigned short* __restrict__ Qh,
                          unsigned short* __restrict__ Vh)
{
    __shared__ unsigned short ms[64 * 392];   // pitch 392 breaks bank alias
    const int lane = threadIdx.x & 63, w = threadIdx.x >> 6;
    const int m0 = blockIdx.x * 64 + w * 16;
    const int lr = lane & 15, g = lane >> 4;
    f32x4 acc[24];
    #pragma unroll
    for (int n = 0; n < 24; ++n) acc[n] = (f32x4){0.f, 0.f, 0.f, 0.f};
    #pragma unroll
    for (int kk = 0; kk < 4; ++kk) {
        const bf16x8 a = *(const bf16x8*)&bondh[(int64_t)(m0 + lr) * 128 + kk * 32 + g * 8];
        #pragma unroll
        for (int n = 0; n < 24; ++n) {
            const bf16x8 b = *(const bf16x8*)&Wt[(n * 16 + lr) * 128 + kk * 32 + g * 8];
            acc[n] = __builtin_amdgcn_mfma_f32_16x16x32_bf16(a, b, acc[n], 0, 0, 0);
        }
    }
    #pragma unroll
    for (int n = 0; n < 24; ++n)
        #pragma unroll
        for (int r = 0; r < 4; ++r)
            ms[(w * 16 + g * 4 + r) * 392 + n * 16 + lr] = f2bf(acc[n][r]);
    __syncthreads();
    // write out: row-major 64x384, routed to K/Q/V
    for (int idx = threadIdx.x; idx < 64 * 48; idx += 256) {
        const int row = idx / 48, c8 = (idx % 48) * 8;
        const int e = blockIdx.x * 64 + row;
        const uint4 v = *(const uint4*)&ms[row * 392 + c8];
        unsigned short* dst = (c8 < 128) ? Kh : (c8 < 256) ? Qh : Vh;
        *(uint4*)&dst[(int64_t)e * 128 + (c8 & 127)] = v;
    }
}

// ---------------------------------------------------------------------------
// Kernel 4: FUSED per-edge attention + aggregation + he + LN1 (-> bf16 h)
// ---------------------------------------------------------------------------
__launch_bounds__(256)
__global__ void edge_att_kernel(const unsigned short* __restrict__ Kh,
                                const unsigned short* __restrict__ Qh,
                                const unsigned short* __restrict__ Vh,
                                const float* __restrict__ aeT,
                                const int* __restrict__ bins,
                                const int* __restrict__ ikj,
                                const int* __restrict__ slot,
                                const int* __restrict__ offs,
                                const int* __restrict__ cnt,
                                const float* __restrict__ battn,
                                const float* __restrict__ disW,
                                const float* __restrict__ bond,
                                const float* __restrict__ g1,
                                const float* __restrict__ b1,
                                float* __restrict__ he,
                                unsigned short* __restrict__ hbf)
{
    __shared__ float aeL[CLS * D_DIM];
    for (int i = threadIdx.x; i < CLS * D_DIM; i += 256) aeL[i] = aeT[i];
    __syncthreads();
    const int wid  = threadIdx.x >> 6;
    const int lane = threadIdx.x & 63;
    const int e = blockIdx.x * 4 + wid;
    const int d0 = lane * 2;
    const int h  = lane >> 3;
    const float dw = disW[h];

    unsigned qw = *(const unsigned*)&Qh[(int64_t)e * D_DIM + d0];
    float q0, q1; bf2x(qw, q0, q1);

    float acc0 = 0.f, acc1 = 0.f, den = 0.f;
    const int start = offs[e], n = cnt[e];
    for (int s = 0; s < n; ++s) {
        const int t   = slot[start + s];
        const int ekj = ikj[t];
        const int bin = bins[t];
        const float ae0 = aeL[bin * D_DIM + d0];
        const float ae1 = aeL[bin * D_DIM + d0 + 1];
        unsigned kw = *(const unsigned*)&Kh[(int64_t)ekj * D_DIM + d0];
        float k0, k1; bf2x(kw, k0, k1);
        float pd = (k0 + ae0) * (q0 + ae0) + (k1 + ae1) * (q1 + ae1);
        pd += __shfl_xor(pd, 1);
        pd += __shfl_xor(pd, 2);
        pd += __shfl_xor(pd, 4);
        const float ex = expf(pd * 0.25f + battn[ekj] * dw);
        den += ex;
        unsigned vw = *(const unsigned*)&Vh[(int64_t)ekj * D_DIM + d0];
        float v0, v1; bf2x(vw, v0, v1);
        acc0 += ex * (v0 + ae0);
        acc1 += ex * (v1 + ae1);
    }
    const float inv = (den > 0.f) ? 1.f / den : 0.f;
    const int64_t base = (int64_t)e * D_DIM;
    const float x0 = acc0 * inv + bond[base + d0];
    const float x1 = acc1 * inv + bond[base + d0 + 1];
    he[base + d0]     = x0;
    he[base + d0 + 1] = x1;
    float sum = x0 + x1;
    #pragma unroll
    for (int o = 32; o > 0; o >>= 1) sum += __shfl_xor(sum, o);
    const float mean = sum * (1.f / 128.f);
    const float dx0 = x0 - mean, dx1 = x1 - mean;
    float var = dx0 * dx0 + dx1 * dx1;
    #pragma unroll
    for (int o = 32; o > 0; o >>= 1) var += __shfl_xor(var, o);
    const float rs = rsqrtf(var * (1.f / 128.f) + 1e-5f);
    const float h0v = dx0 * rs * g1[d0]     + b1[d0];
    const float h1v = dx1 * rs * g1[d0 + 1] + b1[d0 + 1];
    *(unsigned*)&hbf[base + d0] =
        (unsigned)f2bf(h0v) | ((unsigned)f2bf(h1v) << 16);
}

// ---------------------------------------------------------------------------
// FFN GEMM1 (MFMA): mid[E,256] = relu(h @ W1)
// ---------------------------------------------------------------------------
__launch_bounds__(256)
__global__ void ffn1_mfma(const unsigned short* __restrict__ hbf,
                          const unsigned short* __restrict__ W1t,
                          unsigned short* __restrict__ mid)
{
    __shared__ unsigned short ms[64 * 256];
    const int lane = threadIdx.x & 63, w = threadIdx.x >> 6;
    const int m0 = blockIdx.x * 64 + w * 16;
    const int lr = lane & 15, g = lane >> 4;
    f32x4 acc[16];
    #pragma unroll
    for (int n = 0; n < 16; ++n) acc[n] = (f32x4){0.f, 0.f, 0.f, 0.f};
    for (int kk = 0; kk < 4; ++kk) {
        const bf16x8 a = *(const bf16x8*)&hbf[(int64_t)(m0 + lr) * 128 + kk * 32 + g * 8];
        #pragma unroll
        for (int n = 0; n < 16; ++n) {
            const bf16x8 b = *(const bf16x8*)&W1t[(n * 16 + lr) * 128 + kk * 32 + g * 8];
            acc[n] = __builtin_amdgcn_mfma_f32_16x16x32_bf16(a, b, acc[n], 0, 0, 0);
        }
    }
    #pragma unroll
    for (int n = 0; n < 16; ++n)
        #pragma unroll
        for (int r = 0; r < 4; ++r) {
            float v = acc[n][r];
            v = v > 0.f ? v : 0.f;
            ms[(w * 16 + g * 4 + r) * 256 + n * 16 + lr] = f2bf(v);
        }
    __syncthreads();
    const int64_t base = (int64_t)blockIdx.x * 64 * 256;
    for (int i = threadIdx.x; i < 64 * 256 / 8; i += 256)
        *(uint4*)&mid[base + (int64_t)i * 8] = *(const uint4*)&ms[i * 8];
}

// ---------------------------------------------------------------------------
// FFN GEMM2 (MFMA) + residual + LN2 -> d_out
// ---------------------------------------------------------------------------
__launch_bounds__(256)
__global__ void ffn2_mfma(const unsigned short* __restrict__ mid,
                          const unsigned short* __restrict__ W2t,
                          const float* __restrict__ he,
                          const float* __restrict__ g2, const float* __restrict__ b2,
                          float* __restrict__ outp)
{
    __shared__ float cs[64][132];
    const int lane = threadIdx.x & 63, w = threadIdx.x >> 6;
    const int m0 = blockIdx.x * 64 + w * 16;
    const int lr = lane & 15, g = lane >> 4;
    f32x4 acc[8];
    #pragma unroll
    for (int n = 0; n < 8; ++n) acc[n] = (f32x4){0.f, 0.f, 0.f, 0.f};
    for (int kk = 0; kk < 8; ++kk) {
        const bf16x8 a = *(const bf16x8*)&mid[(int64_t)(m0 + lr) * 256 + kk * 32 + g * 8];
        #pragma unroll
        for (int n = 0; n < 8; ++n) {
            const bf16x8 b = *(const bf16x8*)&W2t[(n * 16 + lr) * 256 + kk * 32 + g * 8];
            acc[n] = __builtin_amdgcn_mfma_f32_16x16x32_bf16(a, b, acc[n], 0, 0, 0);
        }
    }
    #pragma unroll
    for (int n = 0; n < 8; ++n)
        #pragma unroll
        for (int r = 0; r < 4; ++r)
            cs[w * 16 + g * 4 + r][n * 16 + lr] = acc[n][r];
    __syncthreads();
    for (int i = 0; i < 16; ++i) {
        const int row = w * 16 + i;
        const int64_t rg = (int64_t)(blockIdx.x * 64 + row) * 128;
        float x0 = cs[row][lane]      + he[rg + lane];
        float x1 = cs[row][64 + lane] + he[rg + 64 + lane];
        float s = x0 + x1;
        #pragma unroll
        for (int o = 32; o > 0; o >>= 1) s += __shfl_xor(s, o);
        const float mean = s * (1.f / 128.f);
        const float d0 = x0 - mean, d1 = x1 - mean;
        float v = d0 * d0 + d1 * d1;
        #pragma unroll
        for (int o = 32; o > 0; o >>= 1) v += __shfl_xor(v, o);
        const float rs = rsqrtf(v * (1.f / 128.f) + 1e-5f);
        outp[rg + lane]      = d0 * rs * g2[lane]      + b2[lane];
        outp[rg + 64 + lane] = d1 * rs * g2[lane + 64] + b2[lane + 64];
    }
}

// ---------------------------------------------------------------------------
extern "C" void kernel_launch(void* const* d_in, const int* in_sizes, int n_in,
                              void* d_out, int out_size, void* d_ws, size_t ws_size,
                              hipStream_t stream)
{
    const float* bond     = (const float*)d_in[0];
    const float* pos      = (const float*)d_in[1];
    const float* battn    = (const float*)d_in[2];
    const float* ang_tab  = (const float*)d_in[3];
    const float* ang_in_W = (const float*)d_in[4];
    const float* ang_in_b = (const float*)d_in[5];
    const float* ang2_W   = (const float*)d_in[6];
    const float* ang2_b   = (const float*)d_in[7];
    const float* ang1_W   = (const float*)d_in[8];
    const float* ang1_b   = (const float*)d_in[9];
    const float* k_W      = (const float*)d_in[10];
    const float* q_W      = (const float*)d_in[11];
    const float* v_W      = (const float*)d_in[12];
    const float* dis_W    = (const float*)d_in[13];
    const float* ffn_W1   = (const float*)d_in[14];
    const float* ffn_W2   = (const float*)d_in[15];
    const float* ln1_g    = (const float*)d_in[16];
    const float* ln1_b    = (const float*)d_in[17];
    const float* ln2_g    = (const float*)d_in[18];
    const float* ln2_b    = (const float*)d_in[19];
    const int*   index_kj = (const int*)d_in[20];
    const int*   index_ji = (const int*)d_in[21];
    const int*   idx_i    = (const int*)d_in[22];
    const int*   idx_j    = (const int*)d_in[23];
    const int*   idx_k    = (const int*)d_in[24];

    float* ws = (float*)d_ws;
    // ws layout (float offsets) — ~313 MB, no overlaps (bondh aliases mid)
    int*            bins  = (int*)(ws + 0);          //   400,000
    int*            slot  = (int*)(ws + 400000);     //   400,000
    int*            offs  = (int*)(ws + 800000);     //   200,000
    int*            cnt   = (int*)(ws + 1000000);    //   200,000
    int*            cur   = (int*)(ws + 1200000);    //   200,000
    int*            bsum  = (int*)(ws + 1400000);    //     1,024
    float*          aeT   = ws + 1401088;            //       768
    unsigned short* W1t   = (unsigned short*)(ws + 1401856);   // 32,768 us
    unsigned short* W2t   = (unsigned short*)(ws + 1418240);   // 32,768 us
    unsigned short* Wt    = (unsigned short*)(ws + 1434624);   // 49,152 us
    float*          heb   = ws + 1459200;            // 25,600,000
    unsigned short* hbf   = (unsigned short*)(ws + 27059200); // 25.6M us
    unsigned short* Vh    = (unsigned short*)(ws + 39859200); // 25.6M us
    unsigned short* mid   = (unsigned short*)(ws + 52659200); // 51.2M us
    unsigned short* bondh = mid;                     // aliases mid (disjoint lifetime)

    // d_out doubles as K/Q bf16 storage, then final out
    unsigned short* Kh = (unsigned short*)d_out;
    unsigned short* Qh = Kh + 25600000;
    float*          out = (float*)d_out;

    hipMemsetAsync(cnt, 0, (size_t)E_EDGES * sizeof(int), stream);
    hipMemsetAsync(cur, 0, (size_t)E_EDGES * sizeof(int), stream);

    ang_mlp_kernel<<<1, 256, 0, stream>>>(ang_tab, ang_in_W, ang_in_b,
                                          ang2_W, ang2_b, ang1_W, ang1_b, aeT);
    conv_w_kernel<<<192, 256, 0, stream>>>(k_W, q_W, v_W, ffn_W1, ffn_W2, Wt, W1t, W2t);
    conv_bond_kernel<<<(E_EDGES * D_DIM / 8 + 255) / 256, 256, 0, stream>>>(bond, bondh);
    tri_bins_kernel<<<(T_TRI + 255) / 256, 256, 0, stream>>>(
        pos, idx_i, idx_j, idx_k, index_ji, bins, cnt);

    const int NB = (E_EDGES + 255) / 256;    // 782
    scan1_kernel<<<NB, 256, 0, stream>>>(cnt, offs, bsum);
    scan2_kernel<<<1, 1024, 0, stream>>>(bsum, NB);
    scan3_kernel<<<NB, 256, 0, stream>>>(offs, bsum);
    fill_kernel<<<(T_TRI + 255) / 256, 256, 0, stream>>>(index_ji, offs, cur, slot);

    proj_mfma<<<E_EDGES / 64, 256, 0, stream>>>(bondh, Wt, Kh, Qh, Vh);

    edge_att_kernel<<<E_EDGES / 4, 256, 0, stream>>>(
        Kh, Qh, Vh, aeT, bins, index_kj, slot, offs, cnt,
        battn, dis_W, bond, ln1_g, ln1_b, heb, hbf);

    ffn1_mfma<<<E_EDGES / 64, 256, 0, stream>>>(hbf, W1t, mid);
    ffn2_mfma<<<E_EDGES / 64, 256, 0, stream>>>(mid, W2t, heb, ln2_g, ln2_b, out);
}